// Round 3
// baseline (207.227 us; speedup 1.0000x reference)
//
#include <hip/hip_runtime.h>

#define BS 1024
#define D 128
#define NC 100000
#define NCP 100096           /* padded to 782*128 */
#define NTILES 782
#define S_SCALE 30.0f
#define MARGIN 0.35f
#define GRIDX 96             /* 96*8 = 768 blocks = exactly 3/CU at 32KB LDS */
#define GRID_TOTAL (GRIDX * 8)
#define C_EXP 43.280851226668917f   /* 30 * log2(e); A prescaled by this */

typedef __attribute__((ext_vector_type(8))) short bf16x8;
typedef __attribute__((ext_vector_type(4))) float f32x4;

__device__ __forceinline__ unsigned short f2bf(float f) {
    union { float f; unsigned u; } x; x.f = f;
    unsigned u = x.u;
    u += 0x7FFFu + ((u >> 16) & 1u);   // round-to-nearest-even
    return (unsigned short)(u >> 16);
}

__device__ __forceinline__ float fast_exp2(float x) {
#if __has_builtin(__builtin_amdgcn_exp2f)
    return __builtin_amdgcn_exp2f(x);
#else
    return exp2f(x);
#endif
}

// Async global->LDS, 16B per lane. Dest is wave-uniform base; HW adds lane*16.
__device__ __forceinline__ void gld_lds16(const void* g, void* l) {
    auto gp = (const __attribute__((address_space(1))) unsigned int*)(g);
    auto lp = (__attribute__((address_space(3))) unsigned int*)(l);
    __builtin_amdgcn_global_load_lds(gp, lp, 16, 0, 0);
}

// One wave per input row (4 rows/block): l2-normalize, emit prescaled swizzled
// bf16, exact-f32 pos, counts, and segment-sum into acc[claimer_row].
__global__ void prep_fn(const float* __restrict__ inp, const int* __restrict__ label,
                        const float* __restrict__ wt,
                        unsigned short* __restrict__ fn_sw,
                        float* __restrict__ counts, int* __restrict__ class2slot,
                        float* __restrict__ acc, float* __restrict__ pos) {
    int wv = threadIdx.x >> 6, lane = threadIdx.x & 63;
    int row = blockIdx.x * 4 + wv;     // grid 256 -> 1024 rows
    int c = label[row];
    float2 v  = *(const float2*)(inp + row * D + lane * 2);
    float2 wv2 = *(const float2*)(wt + c * D + lane * 2);

    float s = v.x * v.x + v.y * v.y;
    #pragma unroll
    for (int m = 1; m < 64; m <<= 1) s += __shfl_xor(s, m);
    float inv = 1.0f / fmaxf(sqrtf(s), 1e-12f);
    float a = v.x * inv, b = v.y * inv;

    // swizzled, prescaled bf16 A: granule g=lane>>2 -> slot g^(row&15)
    unsigned pack = (unsigned)f2bf(a * C_EXP) | ((unsigned)f2bf(b * C_EXP) << 16);
    ((unsigned*)fn_sw)[row * 64 + (((lane >> 2) ^ (row & 15)) << 2) + (lane & 3)] = pack;

    // pos: exact f32 cosine with the label's normalized weight row
    float sw_ = wv2.x * wv2.x + wv2.y * wv2.y;
    float dt  = wv2.x * a + wv2.y * b;
    #pragma unroll
    for (int m = 1; m < 64; m <<= 1) { sw_ += __shfl_xor(sw_, m); dt += __shfl_xor(dt, m); }

    int slotrow = 0;
    if (lane == 0) {
        pos[row] = S_SCALE * dt * (1.0f / fmaxf(sqrtf(sw_), 1e-12f));
        atomicAdd(counts + c, 1.0f);
        int prev = atomicCAS(class2slot + c, 0, row + 1);
        slotrow = prev ? (prev - 1) : row;
    }
    slotrow = __shfl(slotrow, 0);
    atomicAdd(acc + slotrow * D + lane * 2,     a);
    atomicAdd(acc + slotrow * D + lane * 2 + 1, b);
}

// 4 waves/block, one weight row per wave: l2-normalize -> swizzled bf16 global.
// Fused weight output: present class -> class mean (acc/cnt), absent -> copy.
__global__ void prep_wn(const float* __restrict__ wt, const float* __restrict__ counts,
                        const int* __restrict__ class2slot, const float* __restrict__ acc,
                        unsigned short* __restrict__ wn_sw, float* __restrict__ outw) {
    int wv = threadIdx.x >> 6, lane = threadIdx.x & 63;
    int row = blockIdx.x * 4 + wv;      // grid 25024 -> 100096 incl. pad
    int t = row >> 7, c = row & 127;
    unsigned* dst = (unsigned*)wn_sw + t * 8192 + c * 64 +
                    (((lane >> 2) ^ (c & 15)) << 2) + (lane & 3);
    if (row < NC) {
        float2 v = *(const float2*)(wt + row * D + lane * 2);
        float s = v.x * v.x + v.y * v.y;
        #pragma unroll
        for (int m = 1; m < 64; m <<= 1) s += __shfl_xor(s, m);
        float inv = 1.0f / fmaxf(sqrtf(s), 1e-12f);
        *dst = (unsigned)f2bf(v.x * inv) | ((unsigned)f2bf(v.y * inv) << 16);
        float cnt = counts[row];
        float2 o;
        if (cnt > 0.0f) {
            int sr = class2slot[row] - 1;
            float rc = 1.0f / cnt;
            o = make_float2(acc[sr * D + lane * 2] * rc, acc[sr * D + lane * 2 + 1] * rc);
        } else {
            o = v;
        }
        *(float2*)(outw + row * D + lane * 2) = o;
    } else {
        *dst = 0u;   // pad classes: zero vector -> e^-30 per col, negligible
    }
}

// Main fused GEMM + exp-accumulate + (last block) loss.
// Single 32KB LDS buffer: A staged once -> af regs, then reused for B tiles.
__global__ __launch_bounds__(256, 3) void main_gemm(
    const unsigned short* __restrict__ fnsw, const unsigned short* __restrict__ wnsw,
    const float* __restrict__ pos, float* __restrict__ sumexp,
    unsigned int* __restrict__ done, float* __restrict__ out) {
    __shared__ __align__(16) short Bs[128 * 128];  // 32 KB
    __shared__ unsigned int sticket;
    int tid = threadIdx.x;
    int lane = tid & 63, w = tid >> 6;
    int quad = lane >> 4, l15 = lane & 15;
    int m0 = (w >> 1) * 64, n0 = (w & 1) * 64;
    int rowbase = blockIdx.y * 128;

    // Prologue: stage A tile through Bs, hoist all 16 A-fragments to regs.
    {
        const char* gA = (const char*)fnsw + rowbase * 256 + w * 8192 + lane * 16;
        char* lA = (char*)Bs + w * 8192;
        #pragma unroll
        for (int j = 0; j < 8; j++) gld_lds16(gA + j * 1024, lA + j * 1024);
    }
    __syncthreads();   // staging drained (compiler emits vmcnt(0) before barrier)
    bf16x8 af[4][4];
    #pragma unroll
    for (int mt = 0; mt < 4; mt++) {
        int row = m0 + mt * 16 + l15;
        #pragma unroll
        for (int ks = 0; ks < 4; ks++)
            af[mt][ks] = *(const bf16x8*)(Bs + (row * 16 + (((ks * 4 + quad)) ^ l15)) * 8);
    }

    float sums[16];
    #pragma unroll
    for (int i = 0; i < 16; i++) sums[i] = 0.0f;

    for (int tile = blockIdx.x; tile < NTILES; tile += GRIDX) {
        __syncthreads();   // prior LDS reads (af prologue / last tile's bf) done
        const char* gB = (const char*)wnsw + tile * 32768 + w * 8192 + lane * 16;
        char* lB = (char*)Bs + w * 8192;
        #pragma unroll
        for (int j = 0; j < 8; j++) gld_lds16(gB + j * 1024, lB + j * 1024);
        __syncthreads();   // staging drained

        #pragma unroll
        for (int nt = 0; nt < 4; nt++) {
            bf16x8 bf[4];
            int brow = n0 + nt * 16 + l15;
            #pragma unroll
            for (int ks = 0; ks < 4; ks++)
                bf[ks] = *(const bf16x8*)(Bs + (brow * 16 + ((ks * 4 + quad) ^ l15)) * 8);
            f32x4 acc[4];
            #pragma unroll
            for (int mt = 0; mt < 4; mt++) acc[mt] = (f32x4){0.f, 0.f, 0.f, 0.f};
            #pragma unroll
            for (int ks = 0; ks < 4; ks++)
                #pragma unroll
                for (int mt = 0; mt < 4; mt++)
                    acc[mt] = __builtin_amdgcn_mfma_f32_16x16x32_bf16(
                        af[mt][ks], bf[ks], acc[mt], 0, 0, 0);
            // epilogue: A was prescaled by 30*log2e -> e^(30cos-30) = 2^(acc - C)
            #pragma unroll
            for (int mt = 0; mt < 4; mt++)
                #pragma unroll
                for (int r = 0; r < 4; r++)
                    sums[mt * 4 + r] += fast_exp2(acc[mt][r] - C_EXP);
        }
    }

    // Reduce partials across the 16 lanes of each quad, one atomic per row per block.
    #pragma unroll
    for (int mt = 0; mt < 4; mt++) {
        #pragma unroll
        for (int r = 0; r < 4; r++) {
            float s = sums[mt * 4 + r];
            s += __shfl_xor(s, 1);
            s += __shfl_xor(s, 2);
            s += __shfl_xor(s, 4);
            s += __shfl_xor(s, 8);
            if (l15 == 0)
                atomicAdd(sumexp + rowbase + m0 + mt * 16 + quad * 4 + r, s);
        }
    }

    // Last block computes the loss.
    __threadfence();
    if (tid == 0) sticket = atomicAdd(done, 1u);
    __syncthreads();
    if (sticket == GRID_TOTAL - 1) {
        __shared__ float red[256];
        float accv = 0.0f;
        #pragma unroll
        for (int i = 0; i < 4; i++) {
            int r = tid + i * 256;
            float se = atomicAdd(&sumexp[r], 0.0f);   // coherent device-scope read
            float p = pos[r];
            float sneg = fmaxf(se - __expf(p - 30.0f), 1e-38f);
            float z = MARGIN + 30.0f + logf(sneg) - p;
            accv += fmaxf(z, 0.0f) + log1pf(__expf(-fabsf(z)));
        }
        red[tid] = accv;
        __syncthreads();
        for (int s = 128; s > 0; s >>= 1) {
            if (tid < s) red[tid] += red[tid + s];
            __syncthreads();
        }
        if (tid == 0) out[0] = red[0] * (1.0f / 1024.0f);
    }
}

extern "C" void kernel_launch(void* const* d_in, const int* in_sizes, int n_in,
                              void* d_out, int out_size, void* d_ws, size_t ws_size,
                              hipStream_t stream) {
    (void)in_sizes; (void)n_in; (void)out_size; (void)ws_size;
    const float* inp   = (const float*)d_in[0];
    const int*   label = (const int*)d_in[1];
    const float* wt    = (const float*)d_in[2];
    float* out = (float*)d_out;

    char* w = (char*)d_ws;
    unsigned short* fn_sw  = (unsigned short*)(w);             // 262,144 B
    unsigned short* wn_sw  = (unsigned short*)(w + 262144);    // 25,624,576 B
    // memset region @ 25,886,720:
    float*        sumexp     = (float*)(w + 25886720);         // 4,096 B
    float*        counts     = (float*)(w + 25890816);         // 400,384 B
    int*          class2slot = (int*)  (w + 26291200);         // 400,384 B
    float*        acc        = (float*)(w + 26691584);         // 524,288 B
    unsigned int* done       = (unsigned int*)(w + 27215872);  // 256 B
    float*        pos        = (float*)(w + 27216128);         // 4,096 B (no memset)

    hipMemsetAsync(w + 25886720, 0, 1329408, stream);

    prep_fn<<<BS / 4, 256, 0, stream>>>(inp, label, wt, fn_sw, counts, class2slot, acc, pos);
    prep_wn<<<NCP / 4, 256, 0, stream>>>(wt, counts, class2slot, acc, wn_sw, out + 1);
    main_gemm<<<dim3(GRIDX, 8), 256, 0, stream>>>(fn_sw, wn_sw, pos, sumexp, done, out);
}

// Round 4
// 183.494 us; speedup vs baseline: 1.1293x; 1.1293x over previous
//
#include <hip/hip_runtime.h>

#define BS 1024
#define D 128
#define NC 100000
#define NCP 100096           /* padded to 782*128 */
#define NTILES 782
#define S_SCALE 30.0f
#define MARGIN 0.35f
#define GRIDX 64             /* 64*8 = 512 blocks = exactly 2/CU at 64KB LDS */
#define GRID_TOTAL (GRIDX * 8)
#define C_EXP 43.280851226668917f   /* 30 * log2(e); A prescaled by this */

typedef __attribute__((ext_vector_type(8))) short bf16x8;
typedef __attribute__((ext_vector_type(4))) float f32x4;

__device__ __forceinline__ unsigned short f2bf(float f) {
    union { float f; unsigned u; } x; x.f = f;
    unsigned u = x.u;
    u += 0x7FFFu + ((u >> 16) & 1u);   // round-to-nearest-even
    return (unsigned short)(u >> 16);
}

__device__ __forceinline__ float fast_exp2(float x) {
#if __has_builtin(__builtin_amdgcn_exp2f)
    return __builtin_amdgcn_exp2f(x);
#else
    return exp2f(x);
#endif
}

// Async global->LDS, 16B per lane. Dest is wave-uniform base; HW adds lane*16.
__device__ __forceinline__ void gld_lds16(const void* g, void* l) {
    auto gp = (const __attribute__((address_space(1))) unsigned int*)(g);
    auto lp = (__attribute__((address_space(3))) unsigned int*)(l);
    __builtin_amdgcn_global_load_lds(gp, lp, 16, 0, 0);
}

// One wave per input row (4 rows/block): l2-normalize, emit prescaled PLAIN
// row-major bf16 (A is register-loaded in gemm, no swizzle), exact-f32 pos,
// counts, and segment-sum into acc[claimer_row].
__global__ void prep_fn(const float* __restrict__ inp, const int* __restrict__ label,
                        const float* __restrict__ wt,
                        unsigned short* __restrict__ fnb,
                        float* __restrict__ counts, int* __restrict__ class2slot,
                        float* __restrict__ acc, float* __restrict__ pos) {
    int wv = threadIdx.x >> 6, lane = threadIdx.x & 63;
    int row = blockIdx.x * 4 + wv;     // grid 256 -> 1024 rows
    int c = label[row];
    float2 v   = *(const float2*)(inp + row * D + lane * 2);
    float2 wv2 = *(const float2*)(wt + c * D + lane * 2);

    float s = v.x * v.x + v.y * v.y;
    #pragma unroll
    for (int m = 1; m < 64; m <<= 1) s += __shfl_xor(s, m);
    float inv = 1.0f / fmaxf(sqrtf(s), 1e-12f);
    float a = v.x * inv, b = v.y * inv;

    // plain row-major prescaled bf16
    unsigned pack = (unsigned)f2bf(a * C_EXP) | ((unsigned)f2bf(b * C_EXP) << 16);
    ((unsigned*)fnb)[row * 64 + lane] = pack;

    // pos: exact f32 cosine with the label's normalized weight row
    float sw_ = wv2.x * wv2.x + wv2.y * wv2.y;
    float dt  = wv2.x * a + wv2.y * b;
    #pragma unroll
    for (int m = 1; m < 64; m <<= 1) { sw_ += __shfl_xor(sw_, m); dt += __shfl_xor(dt, m); }

    int slotrow = 0;
    if (lane == 0) {
        pos[row] = S_SCALE * dt * (1.0f / fmaxf(sqrtf(sw_), 1e-12f));
        atomicAdd(counts + c, 1.0f);
        int prev = atomicCAS(class2slot + c, 0, row + 1);
        slotrow = prev ? (prev - 1) : row;
    }
    slotrow = __shfl(slotrow, 0);
    atomicAdd(acc + slotrow * D + lane * 2,     a);
    atomicAdd(acc + slotrow * D + lane * 2 + 1, b);
}

// 8 rows/block, 32 lanes/row, float4 loads: l2-normalize -> swizzled bf16;
// fused weight output: present class -> mean (acc/cnt), absent -> copy.
__global__ void prep_wn(const float* __restrict__ wt, const float* __restrict__ counts,
                        const int* __restrict__ class2slot, const float* __restrict__ acc,
                        unsigned short* __restrict__ wn_sw, float* __restrict__ outw) {
    int t = threadIdx.x;
    int row = blockIdx.x * 8 + (t >> 5);   // grid 12512 -> 100096 incl. pad
    int l = t & 31;
    int tt = row >> 7, c = row & 127;
    int gi = l >> 1;                        // granule (k-block) 0..15, 2 threads each
    unsigned* dst = (unsigned*)wn_sw + tt * 8192 + c * 64 +
                    (((gi ^ (c & 15)) << 2) + ((l & 1) << 1));
    if (row < NC) {
        float4 v = *(const float4*)(wt + row * D + l * 4);
        float s = v.x * v.x + v.y * v.y + v.z * v.z + v.w * v.w;
        #pragma unroll
        for (int m = 1; m < 32; m <<= 1) s += __shfl_xor(s, m);
        float inv = 1.0f / fmaxf(sqrtf(s), 1e-12f);
        uint2 p;
        p.x = (unsigned)f2bf(v.x * inv) | ((unsigned)f2bf(v.y * inv) << 16);
        p.y = (unsigned)f2bf(v.z * inv) | ((unsigned)f2bf(v.w * inv) << 16);
        *(uint2*)dst = p;
        float cnt = counts[row];
        float4 o;
        if (cnt > 0.0f) {
            int sr = class2slot[row] - 1;
            float rc = 1.0f / cnt;
            float4 av = *(const float4*)(acc + sr * D + l * 4);
            o = make_float4(av.x * rc, av.y * rc, av.z * rc, av.w * rc);
        } else {
            o = v;
        }
        *(float4*)(outw + row * D + l * 4) = o;
    } else {
        *(uint2*)dst = make_uint2(0u, 0u);  // pad classes: zero vec -> e^-30, negligible
    }
}

// Main fused GEMM + exp-accumulate + (last block) loss.
// A fragments register-resident (direct global loads from L2-resident fnb).
// B double-buffered in LDS: prefetch tile t+1 while computing tile t.
__global__ __launch_bounds__(256, 2) void main_gemm(
    const unsigned short* __restrict__ fnb, const unsigned short* __restrict__ wnsw,
    const float* __restrict__ pos, float* __restrict__ sumexp,
    unsigned int* __restrict__ done, float* __restrict__ out) {
    __shared__ __align__(16) short Bs[2][128 * 128];  // 2 x 32 KB
    __shared__ unsigned int sticket;
    __shared__ float red[256];
    int tid = threadIdx.x;
    int lane = tid & 63, w = tid >> 6;
    int quad = lane >> 4, l15 = lane & 15;
    int m0 = (w >> 1) * 64, n0 = (w & 1) * 64;
    int rowbase = blockIdx.y * 128;

    // Prefetch tile 0 into Bs[0].
    {
        const char* gB = (const char*)wnsw + blockIdx.x * 32768 + w * 8192 + lane * 16;
        char* lB = (char*)Bs[0] + w * 8192;
        #pragma unroll
        for (int j = 0; j < 8; j++) gld_lds16(gB + j * 1024, lB + j * 1024);
    }
    // A fragments direct from global (L2-resident, one time).
    bf16x8 af[4][4];
    #pragma unroll
    for (int mt = 0; mt < 4; mt++) {
        int row = rowbase + m0 + mt * 16 + l15;
        #pragma unroll
        for (int ks = 0; ks < 4; ks++)
            af[mt][ks] = *(const bf16x8*)(fnb + row * D + (ks * 4 + quad) * 8);
    }

    float sums[16];
    #pragma unroll
    for (int i = 0; i < 16; i++) sums[i] = 0.0f;

    __syncthreads();   // tile-0 staging drained
    int cur = 0;
    for (int tile = blockIdx.x; tile < NTILES; tile += GRIDX) {
        int next = tile + GRIDX;
        if (next < NTILES) {   // wave-uniform branch
            const char* gB = (const char*)wnsw + next * 32768 + w * 8192 + lane * 16;
            char* lB = (char*)Bs[cur ^ 1] + w * 8192;
            #pragma unroll
            for (int j = 0; j < 8; j++) gld_lds16(gB + j * 1024, lB + j * 1024);
        }
        const short* B = Bs[cur];
        #pragma unroll
        for (int nt = 0; nt < 4; nt++) {
            bf16x8 bf[4];
            int brow = n0 + nt * 16 + l15;
            #pragma unroll
            for (int ks = 0; ks < 4; ks++)
                bf[ks] = *(const bf16x8*)(B + (brow * 16 + ((ks * 4 + quad) ^ l15)) * 8);
            f32x4 acc[4];
            #pragma unroll
            for (int mt = 0; mt < 4; mt++) acc[mt] = (f32x4){0.f, 0.f, 0.f, 0.f};
            #pragma unroll
            for (int ks = 0; ks < 4; ks++)
                #pragma unroll
                for (int mt = 0; mt < 4; mt++)
                    acc[mt] = __builtin_amdgcn_mfma_f32_16x16x32_bf16(
                        af[mt][ks], bf[ks], acc[mt], 0, 0, 0);
            // A prescaled by 30*log2e -> e^(30cos-30) = 2^(acc - C)
            #pragma unroll
            for (int mt = 0; mt < 4; mt++)
                #pragma unroll
                for (int r = 0; r < 4; r++)
                    sums[mt * 4 + r] += fast_exp2(acc[mt][r] - C_EXP);
        }
        __syncthreads();   // drains prefetch (vmcnt) + this tile's ds_reads (lgkm)
        cur ^= 1;
    }

    // Reduce partials across the 16 lanes of each quad, one atomic per row per block.
    #pragma unroll
    for (int mt = 0; mt < 4; mt++) {
        #pragma unroll
        for (int r = 0; r < 4; r++) {
            float s = sums[mt * 4 + r];
            s += __shfl_xor(s, 1);
            s += __shfl_xor(s, 2);
            s += __shfl_xor(s, 4);
            s += __shfl_xor(s, 8);
            if (l15 == 0)
                atomicAdd(sumexp + rowbase + m0 + mt * 16 + quad * 4 + r, s);
        }
    }

    // Last block computes the loss.
    __threadfence();
    if (tid == 0) sticket = atomicAdd(done, 1u);
    __syncthreads();
    if (sticket == GRID_TOTAL - 1) {
        float accv = 0.0f;
        #pragma unroll
        for (int i = 0; i < 4; i++) {
            int r = tid + i * 256;
            float se = atomicAdd(&sumexp[r], 0.0f);   // coherent device-scope read
            float p = pos[r];
            float sneg = fmaxf(se - __expf(p - 30.0f), 1e-38f);
            float z = MARGIN + 30.0f + logf(sneg) - p;
            accv += fmaxf(z, 0.0f) + log1pf(__expf(-fabsf(z)));
        }
        red[tid] = accv;
        __syncthreads();
        for (int s = 128; s > 0; s >>= 1) {
            if (tid < s) red[tid] += red[tid + s];
            __syncthreads();
        }
        if (tid == 0) out[0] = red[0] * (1.0f / 1024.0f);
    }
}

extern "C" void kernel_launch(void* const* d_in, const int* in_sizes, int n_in,
                              void* d_out, int out_size, void* d_ws, size_t ws_size,
                              hipStream_t stream) {
    (void)in_sizes; (void)n_in; (void)out_size; (void)ws_size;
    const float* inp   = (const float*)d_in[0];
    const int*   label = (const int*)d_in[1];
    const float* wt    = (const float*)d_in[2];
    float* out = (float*)d_out;

    char* w = (char*)d_ws;
    unsigned short* fnb    = (unsigned short*)(w);             // 262,144 B
    unsigned short* wn_sw  = (unsigned short*)(w + 262144);    // 25,624,576 B
    // memset region @ 25,886,720:
    float*        sumexp     = (float*)(w + 25886720);         // 4,096 B
    float*        counts     = (float*)(w + 25890816);         // 400,384 B
    int*          class2slot = (int*)  (w + 26291200);         // 400,384 B
    float*        acc        = (float*)(w + 26691584);         // 524,288 B
    unsigned int* done       = (unsigned int*)(w + 27215872);  // 256 B
    float*        pos        = (float*)(w + 27216128);         // 4,096 B (no memset)

    hipMemsetAsync(w + 25886720, 0, 1329408, stream);

    prep_fn<<<BS / 4, 256, 0, stream>>>(inp, label, wt, fnb, counts, class2slot, acc, pos);
    prep_wn<<<NCP / 8, 256, 0, stream>>>(wt, counts, class2slot, acc, wn_sw, out + 1);
    main_gemm<<<dim3(GRIDX, 8), 256, 0, stream>>>(fnb, wn_sw, pos, sumexp, done, out);
}